// Round 7
// baseline (146.166 us; speedup 1.0000x reference)
//
#include <hip/hip_runtime.h>
#include <math.h>

#define CHI 64
#define CHO 64
#define HH 128
#define WW 128
#define NB 4
#define KK 9
#define NOFF 27
#define EPSV 1e-5f
#define PLANE (HH * WW)
#define SP 72                 // LDS ci-stride (shorts) for deform halo tile

typedef float f32x4 __attribute__((ext_vector_type(4)));
typedef short bf16x8 __attribute__((ext_vector_type(8)));
typedef unsigned int u32x4 __attribute__((ext_vector_type(4)));

// fp32 -> bf16 round-to-nearest-even
__device__ __forceinline__ unsigned short f2bf(float f) {
    unsigned u = __float_as_uint(f);
    u += 0x7fff + ((u >> 16) & 1);
    return (unsigned short)(u >> 16);
}
__device__ __forceinline__ float bfl(unsigned u) { return __uint_as_float(u << 16); }
__device__ __forceinline__ float bfh(unsigned u) { return __uint_as_float(u & 0xffff0000u); }

// ---------------- fused prep: x-transpose (blocks 0..511) + weight pack (512..655) ----
// R19 transpose: cross-round ledger algebra showed the old transpose was
// ~64us -- its reads were ci-strided (16 scattered 64B segments per load
// instruction) with 2 blocks/CU: an MSHR-serialized TA storm, same disease
// R15 cured in deform. New layout: each wave-instruction reads CONTIGUOUS px
// of one ci-row (512B dense), packs ci-pairs to u32 in-register, bounces
// through a stride-33-dword LDS tile (writes ~4-way, reads ~free), stores
// dense u32x4 (1KB/wave-instr). All global traffic now full-line dense.
__global__ __launch_bounds__(256) void prep_kernel(const float* __restrict__ x,
                                                   const float* __restrict__ w,
                                                   const float* __restrict__ w_off,
                                                   unsigned short* __restrict__ x_bf,
                                                   unsigned short* __restrict__ w_bf,
                                                   unsigned short* __restrict__ woA) {
    __shared__ __align__(16) unsigned int lds32[128 * 33];   // 16896 B
    if (blockIdx.x < 512) {
        const int id = blockIdx.x;             // b*128 + y
        const int b  = id >> 7;
        const int y  = id & 127;
        const int t  = threadIdx.x;
        const int w4 = t >> 6;                 // wave 0..3
        const int l  = t & 63;
        const int half = l >> 5;
        const int px = (l & 31) * 4;
        const float* xrow = x + (size_t)b * (CHI * PLANE) + y * WW;

#pragma unroll
        for (int i = 0; i < 4; i++) {
            int cp = i * 8 + w4 * 2 + half;    // ci-pair 0..31, each exactly once
            const float* r0 = xrow + (size_t)(2 * cp) * PLANE + px;
            float4 va = *(const float4*)r0;            // ci = 2cp   row, dense 512B/half-wave
            float4 vb = *(const float4*)(r0 + PLANE);  // ci = 2cp+1 row
            unsigned d0 = (unsigned)f2bf(va.x) | ((unsigned)f2bf(vb.x) << 16);
            unsigned d1 = (unsigned)f2bf(va.y) | ((unsigned)f2bf(vb.y) << 16);
            unsigned d2 = (unsigned)f2bf(va.z) | ((unsigned)f2bf(vb.z) << 16);
            unsigned d3 = (unsigned)f2bf(va.w) | ((unsigned)f2bf(vb.w) << 16);
            lds32[(px + 0) * 33 + cp] = d0;
            lds32[(px + 1) * 33 + cp] = d1;
            lds32[(px + 2) * 33 + cp] = d2;
            lds32[(px + 3) * 33 + cp] = d3;
        }
        __syncthreads();
        unsigned short* dst = x_bf + (size_t)id * (WW * 64);
#pragma unroll
        for (int it = 0; it < 4; it++) {
            int idx = it * 256 + t;
            int p = idx >> 3, c8 = idx & 7;
            u32x4 o;
            o[0] = lds32[p * 33 + c8 * 4 + 0];
            o[1] = lds32[p * 33 + c8 * 4 + 1];
            o[2] = lds32[p * 33 + c8 * 4 + 2];
            o[3] = lds32[p * 33 + c8 * 4 + 3];
            *(u32x4*)(dst + p * 64 + c8 * 8) = o;      // dense 1KB per wave-instr
        }
    } else {
        int i = (blockIdx.x - 512) * 256 + threadIdx.x;   // 144*256 = 36864 exactly
        {
            int j    = i & 7;
            int lane = (i >> 3) & 63;
            int ks   = (i >> 9) & 1;
            int ct   = (i >> 10) & 3;
            int kk   = i >> 12;                // 0..8
            int co   = ct * 16 + (lane & 15);
            int ci   = ks * 32 + ((lane >> 4) & 3) * 8 + j;
            w_bf[i]  = f2bf(w[(co * CHI + ci) * KK + kk]);
        }
        if (i < 18432) {
            int j    = i & 7;
            int lane = (i >> 3) & 63;
            int ct   = (i >> 9) & 1;
            int ks   = (i >> 10) & 1;
            int kk   = i >> 11;                // 0..8
            int c    = ct * 16 + (lane & 15);
            int ci   = ks * 32 + (lane >> 4) * 8 + j;
            woA[i]   = (c < NOFF) ? f2bf(w_off[(c * CHI + ci) * KK + kk]) : (unsigned short)0;
        }
    }
}

// ---------------- fused deform: offset-conv MFMA + sample + main conv ----------------
// Unchanged from R18 (passing, 55.8us): separate xs/offs/red LDS arrays,
// offs stride 27, __launch_bounds__(256,4).
__global__ __launch_bounds__(256, 4) void deform_kernel(const unsigned short* __restrict__ x_bf,
                                                        const unsigned short* __restrict__ w_bf,
                                                        const unsigned short* __restrict__ woA,
                                                        const float* __restrict__ b_off,
                                                        float* __restrict__ out,
                                                        float* __restrict__ pstats) {
    const int id    = blockIdx.x;              // 0..1023
    const int slot  = id & 7;
    const int b     = slot >> 1;
    const int rb    = id >> 3;                 // 0..127
    const int h     = (slot & 1) * 64 + (rb >> 1);
    const int whalf = rb & 1;
    const int w0    = whalf * 64;
    const int tid   = threadIdx.x;
    const int lane  = tid & 63;
    const int wave  = __builtin_amdgcn_readfirstlane(tid >> 6);
    const int quad  = lane >> 4, pxin = lane & 15;
    const int pxl   = wave * 16 + pxin;        // block-local pixel 0..63

    __shared__ __align__(16) unsigned short xs[3 * 66 * SP];  // 28512 B
    __shared__ float offs[64 * 27];                           // 6912 B, stride 27
    __shared__ float red[512];                                // 2048 B

    // ---- stage 3x66x64 halo tile from x_bf (dense 16B) ----
    const unsigned short* xb = x_bf + (size_t)b * (PLANE * 64);
#pragma unroll
    for (int ky = 0; ky < 3; ky++) {
        int hr = h - 1 + ky;
        for (int base = tid; base < 528; base += 256) {          // 66 cols x 8 ci-blocks
            int col = base >> 3, ci8 = base & 7;
            int wc  = w0 - 1 + col;
            bool ok = ((unsigned)hr < HH) && ((unsigned)wc < WW);
            u32x4 v = {0u, 0u, 0u, 0u};
            if (ok) v = *(const u32x4*)(xb + ((size_t)(hr * WW + wc)) * 64 + ci8 * 8);
            *(u32x4*)&xs[(ky * 66 + col) * SP + ci8 * 8] = v;
        }
    }
    __syncthreads();

    // ---- offset conv: 36 MFMAs/wave -> 27 channels x this wave's 16 px ----
    f32x4 oacc0 = {0.f, 0.f, 0.f, 0.f};
    f32x4 oacc1 = {0.f, 0.f, 0.f, 0.f};
#pragma unroll 3
    for (int kk = 0; kk < KK; kk++) {
        const int ky = kk / 3, kx = kk - ky * 3;
#pragma unroll
        for (int ks = 0; ks < 2; ks++) {
            const bf16x8* wa = (const bf16x8*)woA + (size_t)((kk * 2 + ks) * 2) * 64;
            bf16x8 A0 = wa[lane];
            bf16x8 A1 = wa[64 + lane];
            bf16x8 B = *(const bf16x8*)&xs[(ky * 66 + wave * 16 + pxin + kx) * SP
                                           + ks * 32 + quad * 8];
            oacc0 = __builtin_amdgcn_mfma_f32_16x16x32_bf16(A0, B, oacc0, 0, 0, 0);
            oacc1 = __builtin_amdgcn_mfma_f32_16x16x32_bf16(A1, B, oacc1, 0, 0, 0);
        }
    }

    // ---- park offsets in LDS: offs[px_local][ch], stride 27 (conflict-free) ----
#pragma unroll
    for (int r = 0; r < 4; r++) {
        int c0 = quad * 4 + r;
        offs[pxl * 27 + c0] = oacc0[r];
        int c1 = 16 + quad * 4 + r;
        if (c1 < NOFF) offs[pxl * 27 + c1] = oacc1[r];
    }
    __syncthreads();

    // ---- main gather + MFMA loop (R15 structure, offsets from LDS) ----
    f32x4 acc[4];
#pragma unroll
    for (int t = 0; t < 4; t++) acc[t] = (f32x4){0.f, 0.f, 0.f, 0.f};

    const int wpix = w0 + wave * 16 + pxin;    // this lane's pixel (x coord)
    const unsigned short* xbq = xb + quad * 8;

#pragma unroll 3
    for (int kk = 0; kk < KK; kk++) {
        const int ky = kk / 3, kx = kk % 3;
        float dyv = offs[pxl * 27 + 2 * kk]     + b_off[2 * kk];
        float dxv = offs[pxl * 27 + 2 * kk + 1] + b_off[2 * kk + 1];
        float mov = offs[pxl * 27 + 18 + kk]    + b_off[18 + kk];

        // ---- bilinear params for this lane's pixel ----
        float m   = 1.f / (1.f + __expf(-mov));
        float py  = (float)(h - 1 + ky) + dyv;
        float px_ = (float)(wpix - 1 + kx) + dxv;
        float fy0 = floorf(py), fx0 = floorf(px_);
        float wy = py - fy0, wx = px_ - fx0;
        int y0 = (int)fy0, x0 = (int)fx0;
        int y1 = y0 + 1, x1 = x0 + 1;
        bool vy0 = (unsigned)y0 < HH, vy1 = (unsigned)y1 < HH;
        bool vx0 = (unsigned)x0 < WW, vx1 = (unsigned)x1 < WW;
        float a00 = (vy0 && vx0) ? (1.f - wy) * (1.f - wx) * m : 0.f;
        float a01 = (vy0 && vx1) ? (1.f - wy) * wx * m : 0.f;
        float a10 = (vy1 && vx0) ? wy * (1.f - wx) * m : 0.f;
        float a11 = (vy1 && vx1) ? wy * wx * m : 0.f;
        int cy0 = min(max(y0, 0), HH - 1), cy1 = min(max(y1, 0), HH - 1);
        int cx0 = min(max(x0, 0), WW - 1), cx1 = min(max(x1, 0), WW - 1);
        const unsigned o00 = ((unsigned)(cy0 * WW + cx0)) << 6;
        const unsigned o01 = ((unsigned)(cy0 * WW + cx1)) << 6;
        const unsigned o10 = ((unsigned)(cy1 * WW + cx0)) << 6;
        const unsigned o11 = ((unsigned)(cy1 * WW + cx1)) << 6;

        // ---- 8 dense 16B gathers: 4 corners x 2 ks-halves ----
        u32x4 g00a = *(const u32x4*)(xbq + o00);
        u32x4 g01a = *(const u32x4*)(xbq + o01);
        u32x4 g10a = *(const u32x4*)(xbq + o10);
        u32x4 g11a = *(const u32x4*)(xbq + o11);
        u32x4 g00b = *(const u32x4*)(xbq + o00 + 32);
        u32x4 g01b = *(const u32x4*)(xbq + o01 + 32);
        u32x4 g10b = *(const u32x4*)(xbq + o10 + 32);
        u32x4 g11b = *(const u32x4*)(xbq + o11 + 32);

        // ---- A fragments for all 4 co-tiles x 2 ks (L2-hot table) ----
        const bf16x8* wb = (const bf16x8*)w_bf + (size_t)(kk * 8) * 64;
        bf16x8 A[8];
#pragma unroll
        for (int q = 0; q < 8; q++) A[q] = wb[q * 64 + lane];

        // ---- bilinear combine in fp32, round to bf16 B fragments ----
        bf16x8 B0, B1;
#pragma unroll
        for (int d = 0; d < 4; d++) {
            float tl = a00 * bfl(g00a[d]) + a01 * bfl(g01a[d])
                     + a10 * bfl(g10a[d]) + a11 * bfl(g11a[d]);
            float th = a00 * bfh(g00a[d]) + a01 * bfh(g01a[d])
                     + a10 * bfh(g10a[d]) + a11 * bfh(g11a[d]);
            B0[2 * d]     = (short)f2bf(tl);
            B0[2 * d + 1] = (short)f2bf(th);
            float ul = a00 * bfl(g00b[d]) + a01 * bfl(g01b[d])
                     + a10 * bfl(g10b[d]) + a11 * bfl(g11b[d]);
            float uh = a00 * bfh(g00b[d]) + a01 * bfh(g01b[d])
                     + a10 * bfh(g10b[d]) + a11 * bfh(g11b[d]);
            B1[2 * d]     = (short)f2bf(ul);
            B1[2 * d + 1] = (short)f2bf(uh);
        }

        // ---- 8 MFMAs: all co-tiles, both ks halves ----
#pragma unroll
        for (int t = 0; t < 4; t++) {
            acc[t] = __builtin_amdgcn_mfma_f32_16x16x32_bf16(A[t * 2 + 0], B0, acc[t], 0, 0, 0);
            acc[t] = __builtin_amdgcn_mfma_f32_16x16x32_bf16(A[t * 2 + 1], B1, acc[t], 0, 0, 0);
        }
    }

    // ---- output write: px = wave*16 + pxin, co = t*16 + quad*4 + r ----
#pragma unroll
    for (int t = 0; t < 4; t++) {
#pragma unroll
        for (int r = 0; r < 4; r++) {
            int co = t * 16 + quad * 4 + r;
            out[(((size_t)b * CHO + co) * HH + h) * WW + w0 + wave * 16 + pxin] =
                acc[t][r];
        }
    }

    // ---- fused per-block channel stats (sum, sum^2 over this block's 64 px) ----
#pragma unroll
    for (int t = 0; t < 4; t++) {
#pragma unroll
        for (int r = 0; r < 4; r++) {
            float s  = acc[t][r];
            float s2 = s * s;
#pragma unroll
            for (int mk = 1; mk < 16; mk <<= 1) {
                s  += __shfl_xor(s, mk, 64);
                s2 += __shfl_xor(s2, mk, 64);
            }
            if (pxin == 0) {
                int co = t * 16 + quad * 4 + r;
                red[(0 * 4 + wave) * 64 + co] = s;
                red[(1 * 4 + wave) * 64 + co] = s2;
            }
        }
    }
    __syncthreads();
    if (tid < 128) {
        int part = tid >> 6, idx = tid & 63;
        float v = red[(part * 4 + 0) * 64 + idx] + red[(part * 4 + 1) * 64 + idx]
                + red[(part * 4 + 2) * 64 + idx] + red[(part * 4 + 3) * 64 + idx];
        pstats[(size_t)(part * 64 + idx) * 1024 + id] = v;   // transposed: coalesced reduce
    }
}

// ---------------- fused stats-reduce + BN + ReLU ----------------
// Unchanged from R18 (passing).
__global__ __launch_bounds__(256) void statsbn_kernel(float* __restrict__ y,
                                                      const float* __restrict__ pstats,
                                                      const float* __restrict__ bias,
                                                      const float* __restrict__ gamma,
                                                      const float* __restrict__ beta) {
    const int co  = blockIdx.x & 63;
    const int seg = blockIdx.x >> 6;           // 0..7
    const int t   = threadIdx.x;

    // ---- phase 1: per-channel stats (same order as old reduce_kernel) ----
    const float* ps  = pstats + (size_t)co * 1024;
    const float* ps2 = pstats + (size_t)(64 + co) * 1024;
    float s  = ps[t]  + ps[t + 256]  + ps[t + 512]  + ps[t + 768];
    float s2 = ps2[t] + ps2[t + 256] + ps2[t + 512] + ps2[t + 768];
#pragma unroll
    for (int o = 32; o > 0; o >>= 1) {
        s  += __shfl_down(s, o, 64);
        s2 += __shfl_down(s2, o, 64);
    }
    __shared__ float ls[8];
    int lane = t & 63, wv = t >> 6;
    if (lane == 0) { ls[wv] = s; ls[4 + wv] = s2; }
    __syncthreads();
    float S0 = ls[0] + ls[1] + ls[2] + ls[3];
    float S2 = ls[4] + ls[5] + ls[6] + ls[7];
    float bi = bias[co];
    float Sb  = S0 + 65536.f * bi;                       // sum(v+b)
    float S2b = S2 + 2.f * bi * S0 + 65536.f * bi * bi;  // sum((v+b)^2)
    const float inv_n = 1.f / 65536.f;
    float mean = Sb * inv_n;
    float var  = S2b * inv_n - mean * mean;
    float sc = gamma[co] * rsqrtf(var + EPSV);
    float sh = beta[co] - mean * sc + bi * sc;           // y stored raw

    // ---- phase 2: BN+ReLU over this block's slice (8 float4/thread) ----
    const int b = seg >> 1, half = seg & 1;
    float4* p = (float4*)(y + ((size_t)(b * CHO + co)) * PLANE + half * 8192);
#pragma unroll
    for (int it = 0; it < 8; it++) {
        float4 v = p[it * 256 + t];
        v.x = fmaxf(fmaf(v.x, sc, sh), 0.f);
        v.y = fmaxf(fmaf(v.y, sc, sh), 0.f);
        v.z = fmaxf(fmaf(v.z, sc, sh), 0.f);
        v.w = fmaxf(fmaf(v.w, sc, sh), 0.f);
        p[it * 256 + t] = v;
    }
}

extern "C" void kernel_launch(void* const* d_in, const int* in_sizes, int n_in,
                              void* d_out, int out_size, void* d_ws, size_t ws_size,
                              hipStream_t stream) {
    const float* x     = (const float*)d_in[0];
    const float* w_off = (const float*)d_in[1];
    const float* b_off = (const float*)d_in[2];
    const float* wmat  = (const float*)d_in[3];
    const float* bvec  = (const float*)d_in[4];
    const float* gamma = (const float*)d_in[5];
    const float* beta  = (const float*)d_in[6];
    float* out = (float*)d_out;

    char* ws = (char*)d_ws;
    unsigned short* w_bf  = (unsigned short*)(ws + 1024);   // 73728 B
    unsigned short* woA   = (unsigned short*)(ws + 74752);  // 36864 B
    unsigned short* x_bf  = (unsigned short*)(ws + 139264); // 8388608 B
    float* pstats         = (float*)(ws + 8527872);         // 524288 B -> 9052160 total

    prep_kernel<<<656, 256, 0, stream>>>(x, wmat, w_off, x_bf, w_bf, woA);
    deform_kernel<<<1024, 256, 0, stream>>>(x_bf, w_bf, woA, b_off, out, pstats);
    statsbn_kernel<<<512, 256, 0, stream>>>(out, pstats, bvec, gamma, beta);
}